// Round 1
// baseline (26.328 us; speedup 1.0000x reference)
//
#include <hip/hip_runtime.h>

#define N_PER_BATCH (512 * 512)        // 262144
#define BLOCKS_PER_BATCH 16
#define NBATCH 64
#define THREADS 256
// per thread: 262144 / (16 * 256) = 64 elements = 16 float4 loads per array

__global__ __launch_bounds__(THREADS) void dice_stage1(
    const float* __restrict__ pred, const float* __restrict__ tgt,
    float* __restrict__ partial) {
    const int b  = blockIdx.x / BLOCKS_PER_BATCH;
    const int cb = blockIdx.x % BLOCKS_PER_BATCH;

    const float4* p4 = reinterpret_cast<const float4*>(pred + (size_t)b * N_PER_BATCH);
    const float4* t4 = reinterpret_cast<const float4*>(tgt  + (size_t)b * N_PER_BATCH);

    // this block covers 16384 elements = 4096 float4
    const int base = cb * (N_PER_BATCH / BLOCKS_PER_BATCH / 4);

    float ps = 0.f, ts = 0.f, is = 0.f;
#pragma unroll
    for (int i = 0; i < 16; ++i) {
        const int idx = base + i * THREADS + threadIdx.x;
        const float4 p = p4[idx];
        const float4 t = t4[idx];
        ps += (p.x + p.y) + (p.z + p.w);
        ts += (t.x + t.y) + (t.z + t.w);
        is += (p.x * t.x + p.y * t.y) + (p.z * t.z + p.w * t.w);
    }

    // wave64 butterfly reduce
#pragma unroll
    for (int off = 32; off > 0; off >>= 1) {
        ps += __shfl_down(ps, off, 64);
        ts += __shfl_down(ts, off, 64);
        is += __shfl_down(is, off, 64);
    }

    __shared__ float s[3][4];
    const int wid  = threadIdx.x >> 6;
    const int lane = threadIdx.x & 63;
    if (lane == 0) { s[0][wid] = ps; s[1][wid] = ts; s[2][wid] = is; }
    __syncthreads();
    if (threadIdx.x == 0) {
        const float P = (s[0][0] + s[0][1]) + (s[0][2] + s[0][3]);
        const float T = (s[1][0] + s[1][1]) + (s[1][2] + s[1][3]);
        const float I = (s[2][0] + s[2][1]) + (s[2][2] + s[2][3]);
        float* o = partial + ((size_t)b * BLOCKS_PER_BATCH + cb) * 3;
        o[0] = P; o[1] = T; o[2] = I;
    }
}

__global__ __launch_bounds__(64) void dice_stage2(
    const float* __restrict__ partial, float* __restrict__ out) {
    const int b = threadIdx.x;  // 0..63 — one lane per batch
    float P = 0.f, T = 0.f, I = 0.f;
#pragma unroll
    for (int i = 0; i < BLOCKS_PER_BATCH; ++i) {
        const float* p = partial + ((size_t)b * BLOCKS_PER_BATCH + i) * 3;
        P += p[0]; T += p[1]; I += p[2];
    }
    const float dice_loss = 1.0f - (2.0f * I + 1.0f) / (P + T + 1.0f);
    const float zero_loss = P / (float)N_PER_BATCH;
    // target entries are 0/1 -> T is an exact small integer in fp32, so ==0 is exact
    float loss = (T == 0.0f) ? zero_loss : dice_loss;
#pragma unroll
    for (int off = 32; off > 0; off >>= 1) loss += __shfl_down(loss, off, 64);
    if (b == 0) out[0] = loss * (1.0f / (float)NBATCH);
}

extern "C" void kernel_launch(void* const* d_in, const int* in_sizes, int n_in,
                              void* d_out, int out_size, void* d_ws, size_t ws_size,
                              hipStream_t stream) {
    const float* pred = (const float*)d_in[0];
    const float* tgt  = (const float*)d_in[1];
    float* out = (float*)d_out;
    float* partial = (float*)d_ws;  // 64 * 16 * 3 floats = 12 KiB

    dice_stage1<<<NBATCH * BLOCKS_PER_BATCH, THREADS, 0, stream>>>(pred, tgt, partial);
    dice_stage2<<<1, 64, 0, stream>>>(partial, out);
}